// Round 11
// baseline (1257.835 us; speedup 1.0000x reference)
//
#include <hip/hip_runtime.h>
#include <math.h>

// DeepFeatureLoss: B=2, N=4096, D=32, fp32 in/out.
// out[0..1] = ce_loss[b], out[2..3] = reg_loss[b].
//
// R11 = R6 EXACT (best, 33.0us) + 3 ablation PROBE kernels writing to ws
// scratch only, each looping the kB inner loop 4x (amplified above the
// ~39us fill dispatches so rocprof top-5 shows them):
//   probe<0> full   : exact kB loop            -> 4 x kB_loop cost
//   probe<1> noexp  : exp2 -> identity         -> isolates trans exec
//   probe<2> noload : no in-loop global loads  -> isolates load/waitcnt
//     (asm volatile "+v" touches defeat hoist/CSE, rule #17)
// Readout: full4/4 = steady-state kB; compare noexp4/noload4 vs full4.
//
// ws (floats): pp1[0,32768) pp2[32768,65536) fragB[65536,196608)
// fragA[196608,327680) regp[327680,335872) probe scratch[335872,...).

#define NPTS 4096
#define ROWS_TOT 8192
#define DF 32
#define NTILE 512                // 16-row i-tiles across both batches
#define PROBE_REPS 4

#define L2E  1.4426950408889634f
#define LN2  0.6931471805599453f
#define FSC  1.6986436f          // sqrt(2*log2e)
#define PSC  240.2244f           // 200*sqrt(log2e)

typedef _Float16 half8 __attribute__((ext_vector_type(8)));
typedef float f4 __attribute__((ext_vector_type(4)));

// ---- kA: prep (identical to R6) ----
__global__ void kA_prep(const float* __restrict__ pts,
                        const float* __restrict__ f1g,
                        const float* __restrict__ f2g,
                        float* __restrict__ pp1, float* __restrict__ pp2,
                        _Float16* __restrict__ fragA, _Float16* __restrict__ fragB,
                        float* __restrict__ regp, float* __restrict__ out) {
    const int r = blockIdx.x * 64 + threadIdx.x;     // 0..8191
    if (r < 4) out[r] = 0.0f;
    const int jt = r >> 4;                           // global tile id 0..511
    const int c  = r & 15;                           // row/col within tile

    float n1, n2, reg1, reg2;
    {
        const float4* f2v = (const float4*)(f2g + (size_t)r * DF);
        float vals[32];
        float s = 0.0f;
#pragma unroll
        for (int q = 0; q < 8; ++q) {
            float4 v = f2v[q];
            vals[4*q]=v.x; vals[4*q+1]=v.y; vals[4*q+2]=v.z; vals[4*q+3]=v.w;
            s += v.x*v.x + v.y*v.y + v.z*v.z + v.w*v.w;
        }
        n2 = s;
        reg2 = s - vals[0]*vals[0] - vals[1]*vals[1] - vals[2]*vals[2];
        half8* fv = (half8*)fragB;
#pragma unroll
        for (int kb = 0; kb < 4; ++kb) {             // lane-ordered slot
            half8 h;
#pragma unroll
            for (int i = 0; i < 8; ++i) h[i] = (_Float16)(vals[kb*8+i] * FSC);
            fv[(size_t)jt*64 + kb*16 + c] = h;
        }
    }
    {
        const float4* f1v = (const float4*)(f1g + (size_t)r * DF);
        float vals[32];
        float s = 0.0f;
#pragma unroll
        for (int q = 0; q < 8; ++q) {
            float4 v = f1v[q];
            vals[4*q]=v.x; vals[4*q+1]=v.y; vals[4*q+2]=v.z; vals[4*q+3]=v.w;
            s += v.x*v.x + v.y*v.y + v.z*v.z + v.w*v.w;
        }
        n1 = s;
        reg1 = s - vals[0]*vals[0] - vals[1]*vals[1] - vals[2]*vals[2];
        half8* fv = (half8*)fragA;
#pragma unroll
        for (int kb = 0; kb < 4; ++kb) {
            half8 h;
#pragma unroll
            for (int i = 0; i < 8; ++i) h[i] = (_Float16)(vals[kb*8+i] * FSC);
            fv[(size_t)jt*64 + kb*16 + c] = h;
        }
    }
    const float* pp = pts + (size_t)r * 3;
    const float px = pp[0]*PSC, py = pp[1]*PSC, pz = pp[2]*PSC;
    ((float4*)pp1)[r] = make_float4(px, py, pz, n1 * L2E);
    ((float4*)pp2)[r] = make_float4(px, py, pz, n2 * L2E);
    regp[r] = reg1 + reg2;
}

// ---- kB: EXACT R6 (output-producing) ----
__launch_bounds__(512)
__global__ void kB_main(const float* __restrict__ pp1,
                        const float* __restrict__ pp2,
                        const _Float16* __restrict__ fragA,
                        const _Float16* __restrict__ fragB,
                        const float* __restrict__ regp,
                        const float* __restrict__ wg,
                        float* __restrict__ out) {
    __shared__ float sS[8][16], sT[8][16], sF[8][16];

    const int tid = threadIdx.x;
    const int l = tid & 63, wv = tid >> 6;           // wave 0..7
    const int i_tile = blockIdx.x;                   // 0..511
    const int b = i_tile >> 8;
    const int i0g = i_tile * 16;                     // global row base
    const int lr = l & 15, lk = l >> 4;

    const half8 afrag = ((const half8*)fragA)[(size_t)i_tile * 64 + l];

    const int rbase = i0g + lk * 4;                  // this lane's 4 rows
    const float4 q0 = ((const float4*)pp1)[rbase + 0];
    const float4 q1 = ((const float4*)pp1)[rbase + 1];
    const float4 q2 = ((const float4*)pp1)[rbase + 2];
    const float4 q3 = ((const float4*)pp1)[rbase + 3];
    const f4 qx = {q0.x, q1.x, q2.x, q3.x};
    const f4 qy = {q0.y, q1.y, q2.y, q3.y};
    const f4 qz = {q0.z, q1.z, q2.z, q3.z};
    const f4 qw = {q0.w, q1.w, q2.w, q3.w};

    const half8*  fbase = (const half8*)fragB + ((size_t)(b * 256 + wv * 32) * 64 + l);
    const float4* pbase = (const float4*)pp2 + (b * NPTS + wv * 512 + lr);

    f4 sp = {0,0,0,0}, tA = {0,0,0,0}, sf = {0,0,0,0};
    const f4 zero = {0.f, 0.f, 0.f, 0.f};

    half8  bfA = fbase[0];
    float4 pwA = pbase[0];
#pragma unroll
    for (int t = 0; t < 32; ++t) {
        half8  bfN = bfA;
        float4 pwN = pwA;
        if (t < 31) {                                // 1-deep prefetch
            bfN = fbase[(t + 1) * 64];
            pwN = pbase[(t + 1) * 16];
        }
        const f4 cc4 = __builtin_amdgcn_mfma_f32_16x16x32_f16(afrag, bfA, zero, 0, 0, 0);
        const f4 fd = cc4 - qw - pwA.w;              // log2e * fea_dist2 (<=0)
        const f4 dx = qx - pwA.x;
        const f4 dy = qy - pwA.y;
        const f4 dz = qz - pwA.z;
        const f4 s  = dx*dx + dy*dy + dz*dz;         // log2e * |dp|^2
        f4 ep, ef;
#pragma unroll
        for (int e = 0; e < 4; ++e) {
            ep[e] = __builtin_amdgcn_exp2f(-s[e]);
            ef[e] = __builtin_amdgcn_exp2f(fd[e]);
        }
        sp += ep;
        tA += ep * fd;
        sf += ef;
        bfA = bfN;
        pwA = pwN;
    }

#pragma unroll
    for (int m = 1; m < 16; m <<= 1) {
#pragma unroll
        for (int e = 0; e < 4; ++e) {
            sp[e] += __shfl_xor(sp[e], m);
            tA[e] += __shfl_xor(tA[e], m);
            sf[e] += __shfl_xor(sf[e], m);
        }
    }
    if (lr == 0) {
#pragma unroll
        for (int e = 0; e < 4; ++e) {
            sS[wv][lk * 4 + e] = sp[e];
            sT[wv][lk * 4 + e] = tA[e];
            sF[wv][lk * 4 + e] = sf[e];
        }
    }
    __syncthreads();

    if (tid < 16) {
        float sp_ = 0.f, tp_ = 0.f, sf_ = 0.f;
#pragma unroll
        for (int w = 0; w < 8; ++w) {
            sp_ += sS[w][tid];
            tp_ += sT[w][tid];
            sf_ += sF[w][tid];
        }
        const int r = i0g + tid;
        const float ce = __logf(sf_) - (tp_ * LN2) / sp_;
        float contrib = wg[r] * ce;
        float rr = regp[r];
#pragma unroll
        for (int m = 1; m < 16; m <<= 1) {
            contrib += __shfl_xor(contrib, m);
            rr      += __shfl_xor(rr, m);
        }
        if (tid == 0) {
            atomicAdd(&out[b],     contrib);
            atomicAdd(&out[2 + b], rr * (1.0f / (29.0f * (float)NPTS)));
        }
    }
}

// ---- probes: MODE 0=full, 1=noexp, 2=noload; 4 reps; scratch-only ----
template <int MODE>
__launch_bounds__(512)
__global__ void kB_probe(const float* __restrict__ pp1,
                         const float* __restrict__ pp2,
                         const _Float16* __restrict__ fragA,
                         const _Float16* __restrict__ fragB,
                         float* __restrict__ scratch) {
    const int tid = threadIdx.x;
    const int l = tid & 63, wv = tid >> 6;
    const int i_tile = blockIdx.x;
    const int b = i_tile >> 8;
    const int i0g = i_tile * 16;
    const int lr = l & 15, lk = l >> 4;

    const half8 afrag = ((const half8*)fragA)[(size_t)i_tile * 64 + l];

    const int rbase = i0g + lk * 4;
    const float4 q0 = ((const float4*)pp1)[rbase + 0];
    const float4 q1 = ((const float4*)pp1)[rbase + 1];
    const float4 q2 = ((const float4*)pp1)[rbase + 2];
    const float4 q3 = ((const float4*)pp1)[rbase + 3];
    const f4 qx = {q0.x, q1.x, q2.x, q3.x};
    const f4 qy = {q0.y, q1.y, q2.y, q3.y};
    const f4 qz = {q0.z, q1.z, q2.z, q3.z};
    const f4 qw = {q0.w, q1.w, q2.w, q3.w};

    const half8*  fbase = (const half8*)fragB + ((size_t)(b * 256 + wv * 32) * 64 + l);
    const float4* pbase = (const float4*)pp2 + (b * NPTS + wv * 512 + lr);

    f4 sp = {0,0,0,0}, tA = {0,0,0,0}, sf = {0,0,0,0};
    const f4 zero = {0.f, 0.f, 0.f, 0.f};

#pragma unroll 1
    for (int rep = 0; rep < PROBE_REPS; ++rep) {
        half8  bfA = fbase[0];          // L2/L1-warm after rep 0
        float4 pwA = pbase[0];
#pragma unroll
        for (int t = 0; t < 32; ++t) {
            half8  bfN = bfA;
            float4 pwN = pwA;
            if (MODE != 2 && t < 31) {               // noload: no in-loop VMEM
                bfN = fbase[(t + 1) * 64];
                pwN = pbase[(t + 1) * 16];
            }
            if (MODE == 2) {
                // defeat hoist/CSE of the loop-invariant operands (rule #17)
                asm volatile("" : "+v"(bfA));
                asm volatile("" : "+v"(pwA.x), "+v"(pwA.y), "+v"(pwA.z), "+v"(pwA.w));
            }
            const f4 cc4 = __builtin_amdgcn_mfma_f32_16x16x32_f16(afrag, bfA, zero, 0, 0, 0);
            const f4 fd = cc4 - qw - pwA.w;
            const f4 dx = qx - pwA.x;
            const f4 dy = qy - pwA.y;
            const f4 dz = qz - pwA.z;
            const f4 s  = dx*dx + dy*dy + dz*dz;
            f4 ep, ef;
#pragma unroll
            for (int e = 0; e < 4; ++e) {
                if (MODE == 1) { ep[e] = -s[e]; ef[e] = fd[e]; }   // exp ablated
                else {
                    ep[e] = __builtin_amdgcn_exp2f(-s[e]);
                    ef[e] = __builtin_amdgcn_exp2f(fd[e]);
                }
            }
            sp += ep;
            tA += ep * fd;
            sf += ef;
            bfA = bfN;
            pwA = pwN;
        }
    }

#pragma unroll
    for (int m = 1; m < 16; m <<= 1) {
#pragma unroll
        for (int e = 0; e < 4; ++e) {
            sp[e] += __shfl_xor(sp[e], m);
            tA[e] += __shfl_xor(tA[e], m);
            sf[e] += __shfl_xor(sf[e], m);
        }
    }
    if (lr == 0) {
        f4* S = (f4*)scratch + ((size_t)(MODE * NTILE + blockIdx.x) * 8 + wv) * 3;
        S[0] = sp; S[1] = tA; S[2] = sf;
    }
}

extern "C" void kernel_launch(void* const* d_in, const int* in_sizes, int n_in,
                              void* d_out, int out_size, void* d_ws, size_t ws_size,
                              hipStream_t stream) {
    const float* pts = (const float*)d_in[0];
    const float* f1  = (const float*)d_in[1];
    const float* f2  = (const float*)d_in[2];
    const float* wg  = (const float*)d_in[3];
    float* out = (float*)d_out;

    float* ws = (float*)d_ws;
    float*     pp1   = ws;                           // 32768
    float*     pp2   = ws + 32768;                   // 32768
    _Float16*  fragB = (_Float16*)(ws + 65536);      // 262144 halves
    _Float16*  fragA = (_Float16*)(ws + 196608);     // 262144 halves
    float*     regp  = ws + 327680;                  // 8192
    float*     scr   = ws + 335872;                  // 3*512*8*12 = 147456

    kA_prep<<<ROWS_TOT / 64, 64, 0, stream>>>(pts, f1, f2, pp1, pp2,
                                              fragA, fragB, regp, out);
    kB_main<<<NTILE, 512, 0, stream>>>(pp1, pp2, fragA, fragB, regp, wg, out);
    kB_probe<0><<<NTILE, 512, 0, stream>>>(pp1, pp2, fragA, fragB, scr);
    kB_probe<1><<<NTILE, 512, 0, stream>>>(pp1, pp2, fragA, fragB, scr);
    kB_probe<2><<<NTILE, 512, 0, stream>>>(pp1, pp2, fragA, fragB, scr);
}

// Round 12
// 28.527 us; speedup vs baseline: 44.0928x; 44.0928x over previous
//
#include <hip/hip_runtime.h>
#include <math.h>

// DeepFeatureLoss: B=2, N=4096, D=32, fp32 in/out.
// out[0..1] = ce_loss[b], out[2..3] = reg_loss[b].
//
// ce_i = log(s_f) - t/s_p  (softmax max pinned at 0; dists <= 0):
//   s_p = sum_j exp(pd_ij), t = sum_j exp(pd_ij)*fd_ij, s_f = sum_j exp(fd_ij)
// exp2 folding: points *PSC, features *FSC, norms *L2E; t *= LN2 at end.
//
// R12 = R6 + MI=2 intensity blocking (single variable):
//   block = (i-pair of 2 tiles = 32 rows) x (j-half of 2048 cols), 8 waves.
//   Each wave: 16 j-tiles; per iter ONE bfrag+pw load feeds TWO MFMAs and
//   two epilogues -> loads/output halved (B-stream 164->82 MB), per-output
//   issue unchanged. Partial sums -> disjoint part[jh] planes; k2 combines.
// Rationale: R10 (+VALU showed 1:1) kills latency-hiding assumption;
// R8 (traffic/8 = null) kills pure-traffic; per-iter load-stall+issue
// model survives -> cut loads per output.
//
// ws (floats): pp1[0,32768) pp2[32768,65536) fragB[65536,196608)
// fragA[196608,327680) regp[327680,335872) part[335872,385024).

#define NPTS 4096
#define ROWS_TOT 8192
#define DF 32

#define L2E  1.4426950408889634f
#define LN2  0.6931471805599453f
#define FSC  1.6986436f          // sqrt(2*log2e)
#define PSC  240.2244f           // 200*sqrt(log2e)

typedef _Float16 half8 __attribute__((ext_vector_type(8)));
typedef float f4 __attribute__((ext_vector_type(4)));

// ---- kA: prep (identical to R6/R11) ----
__global__ void kA_prep(const float* __restrict__ pts,
                        const float* __restrict__ f1g,
                        const float* __restrict__ f2g,
                        float* __restrict__ pp1, float* __restrict__ pp2,
                        _Float16* __restrict__ fragA, _Float16* __restrict__ fragB,
                        float* __restrict__ regp, float* __restrict__ out) {
    const int r = blockIdx.x * 64 + threadIdx.x;     // 0..8191
    if (r < 4) out[r] = 0.0f;
    const int jt = r >> 4;                           // global tile id 0..511
    const int c  = r & 15;                           // row/col within tile

    float n1, n2, reg1, reg2;
    {
        const float4* f2v = (const float4*)(f2g + (size_t)r * DF);
        float vals[32];
        float s = 0.0f;
#pragma unroll
        for (int q = 0; q < 8; ++q) {
            float4 v = f2v[q];
            vals[4*q]=v.x; vals[4*q+1]=v.y; vals[4*q+2]=v.z; vals[4*q+3]=v.w;
            s += v.x*v.x + v.y*v.y + v.z*v.z + v.w*v.w;
        }
        n2 = s;
        reg2 = s - vals[0]*vals[0] - vals[1]*vals[1] - vals[2]*vals[2];
        half8* fv = (half8*)fragB;
#pragma unroll
        for (int kb = 0; kb < 4; ++kb) {             // lane-ordered slot
            half8 h;
#pragma unroll
            for (int i = 0; i < 8; ++i) h[i] = (_Float16)(vals[kb*8+i] * FSC);
            fv[(size_t)jt*64 + kb*16 + c] = h;
        }
    }
    {
        const float4* f1v = (const float4*)(f1g + (size_t)r * DF);
        float vals[32];
        float s = 0.0f;
#pragma unroll
        for (int q = 0; q < 8; ++q) {
            float4 v = f1v[q];
            vals[4*q]=v.x; vals[4*q+1]=v.y; vals[4*q+2]=v.z; vals[4*q+3]=v.w;
            s += v.x*v.x + v.y*v.y + v.z*v.z + v.w*v.w;
        }
        n1 = s;
        reg1 = s - vals[0]*vals[0] - vals[1]*vals[1] - vals[2]*vals[2];
        half8* fv = (half8*)fragA;
#pragma unroll
        for (int kb = 0; kb < 4; ++kb) {
            half8 h;
#pragma unroll
            for (int i = 0; i < 8; ++i) h[i] = (_Float16)(vals[kb*8+i] * FSC);
            fv[(size_t)jt*64 + kb*16 + c] = h;
        }
    }
    const float* pp = pts + (size_t)r * 3;
    const float px = pp[0]*PSC, py = pp[1]*PSC, pz = pp[2]*PSC;
    ((float4*)pp1)[r] = make_float4(px, py, pz, n1 * L2E);
    ((float4*)pp2)[r] = make_float4(px, py, pz, n2 * L2E);
    regp[r] = reg1 + reg2;
}

// ---- kB: (i-pair, j-half) blocks; one B-load feeds two MFMAs ----
__launch_bounds__(512)
__global__ void kB_main(const float* __restrict__ pp1,
                        const float* __restrict__ pp2,
                        const _Float16* __restrict__ fragA,
                        const _Float16* __restrict__ fragB,
                        float* __restrict__ part) {
    __shared__ float sS[8][32], sT[8][32], sF[8][32];

    const int tid = threadIdx.x;
    const int l = tid & 63, wv = tid >> 6;           // wave 0..7
    const int ip = blockIdx.x >> 1;                  // i-pair 0..255
    const int jh = blockIdx.x & 1;                   // j-half 0/1
    const int b  = ip >> 7;
    const int i0g = ip * 32;                         // 32-row base
    const int lr = l & 15, lk = l >> 4;

    const half8 afA = ((const half8*)fragA)[(size_t)(ip * 2)     * 64 + l];
    const half8 afB = ((const half8*)fragA)[(size_t)(ip * 2 + 1) * 64 + l];

    const int rbA = i0g + lk * 4;                    // lane's rows, tile A
    const int rbB = i0g + 16 + lk * 4;               // lane's rows, tile B
    f4 qxA, qyA, qzA, qwA, qxB, qyB, qzB, qwB;
#pragma unroll
    for (int e = 0; e < 4; ++e) {
        const float4 qA = ((const float4*)pp1)[rbA + e];
        const float4 qB = ((const float4*)pp1)[rbB + e];
        qxA[e] = qA.x; qyA[e] = qA.y; qzA[e] = qA.z; qwA[e] = qA.w;
        qxB[e] = qB.x; qyB[e] = qB.y; qzB[e] = qB.z; qwB[e] = qB.w;
    }

    // wave's j range: 16 tiles, jt0 = b*256 + jh*128 + wv*16
    const int jt0 = b * 256 + jh * 128 + wv * 16;
    const int j0  = b * NPTS + jh * 2048 + wv * 256 + lr;
    const half8*  fbase = (const half8*)fragB + ((size_t)jt0 * 64 + l);
    const float4* pbase = (const float4*)pp2 + j0;

    f4 spA = {0,0,0,0}, tAA = {0,0,0,0}, sfA = {0,0,0,0};
    f4 spB = {0,0,0,0}, tAB = {0,0,0,0}, sfB = {0,0,0,0};
    const f4 zero = {0.f, 0.f, 0.f, 0.f};

    half8  bfC = fbase[0];
    float4 pwC = pbase[0];
#pragma unroll
    for (int t = 0; t < 16; ++t) {
        half8  bfN = bfC;
        float4 pwN = pwC;
        if (t < 15) {                                // 1-deep prefetch
            bfN = fbase[(t + 1) * 64];
            pwN = pbase[(t + 1) * 16];
        }
        const f4 ccA = __builtin_amdgcn_mfma_f32_16x16x32_f16(afA, bfC, zero, 0, 0, 0);
        const f4 ccB = __builtin_amdgcn_mfma_f32_16x16x32_f16(afB, bfC, zero, 0, 0, 0);
        {   // epilogue tile A
            const f4 fd = ccA - qwA - pwC.w;
            const f4 dx = qxA - pwC.x;
            const f4 dy = qyA - pwC.y;
            const f4 dz = qzA - pwC.z;
            const f4 s  = dx*dx + dy*dy + dz*dz;
            f4 ep, ef;
#pragma unroll
            for (int e = 0; e < 4; ++e) {
                ep[e] = __builtin_amdgcn_exp2f(-s[e]);
                ef[e] = __builtin_amdgcn_exp2f(fd[e]);
            }
            spA += ep; tAA += ep * fd; sfA += ef;
        }
        {   // epilogue tile B (same B-operand data)
            const f4 fd = ccB - qwB - pwC.w;
            const f4 dx = qxB - pwC.x;
            const f4 dy = qyB - pwC.y;
            const f4 dz = qzB - pwC.z;
            const f4 s  = dx*dx + dy*dy + dz*dz;
            f4 ep, ef;
#pragma unroll
            for (int e = 0; e < 4; ++e) {
                ep[e] = __builtin_amdgcn_exp2f(-s[e]);
                ef[e] = __builtin_amdgcn_exp2f(fd[e]);
            }
            spB += ep; tAB += ep * fd; sfB += ef;
        }
        bfC = bfN;
        pwC = pwN;
    }

    // reduce over the 16 columns (lane bits 0..3), both tiles
#pragma unroll
    for (int m = 1; m < 16; m <<= 1) {
#pragma unroll
        for (int e = 0; e < 4; ++e) {
            spA[e] += __shfl_xor(spA[e], m);
            tAA[e] += __shfl_xor(tAA[e], m);
            sfA[e] += __shfl_xor(sfA[e], m);
            spB[e] += __shfl_xor(spB[e], m);
            tAB[e] += __shfl_xor(tAB[e], m);
            sfB[e] += __shfl_xor(sfB[e], m);
        }
    }
    if (lr == 0) {
#pragma unroll
        for (int e = 0; e < 4; ++e) {
            sS[wv][lk * 4 + e]      = spA[e];
            sT[wv][lk * 4 + e]      = tAA[e];
            sF[wv][lk * 4 + e]      = sfA[e];
            sS[wv][16 + lk * 4 + e] = spB[e];
            sT[wv][16 + lk * 4 + e] = tAB[e];
            sF[wv][16 + lk * 4 + e] = sfB[e];
        }
    }
    __syncthreads();

    if (tid < 32) {
        float sp_ = 0.f, tp_ = 0.f, sf_ = 0.f;
#pragma unroll
        for (int w = 0; w < 8; ++w) {
            sp_ += sS[w][tid];
            tp_ += sT[w][tid];
            sf_ += sF[w][tid];
        }
        float* P = part + (size_t)jh * 3 * ROWS_TOT;
        P[i0g + tid]                = sp_;
        P[ROWS_TOT + i0g + tid]     = tp_;
        P[2 * ROWS_TOT + i0g + tid] = sf_;
    }
}

// ---- k2: combine 2 j-half planes, ce + reg -> out ----
__global__ void k2_final(const float* __restrict__ part,
                         const float* __restrict__ regp,
                         const float* __restrict__ wg,
                         float* __restrict__ out) {
    __shared__ float redc[4], redr[4];
    const int tid = threadIdx.x;
    const int r = blockIdx.x * 256 + tid;
    const int b = r >> 12;

    const float* P0 = part;
    const float* P1 = part + (size_t)3 * ROWS_TOT;
    const float sp_ = P0[r] + P1[r];
    const float tp_ = P0[ROWS_TOT + r] + P1[ROWS_TOT + r];
    const float sf_ = P0[2*ROWS_TOT + r] + P1[2*ROWS_TOT + r];
    const float ce = __logf(sf_) - (tp_ * LN2) / sp_;
    float contrib = wg[r] * ce;
    float rr = regp[r];

#pragma unroll
    for (int off = 32; off > 0; off >>= 1) {
        contrib += __shfl_down(contrib, off);
        rr      += __shfl_down(rr, off);
    }
    const int wave = tid >> 6, lane = tid & 63;
    if (lane == 0) { redc[wave] = contrib; redr[wave] = rr; }
    __syncthreads();
    if (tid == 0) {
        atomicAdd(&out[b],     redc[0] + redc[1] + redc[2] + redc[3]);
        atomicAdd(&out[2 + b], (redr[0] + redr[1] + redr[2] + redr[3])
                               * (1.0f / (29.0f * (float)NPTS)));
    }
}

extern "C" void kernel_launch(void* const* d_in, const int* in_sizes, int n_in,
                              void* d_out, int out_size, void* d_ws, size_t ws_size,
                              hipStream_t stream) {
    const float* pts = (const float*)d_in[0];
    const float* f1  = (const float*)d_in[1];
    const float* f2  = (const float*)d_in[2];
    const float* wg  = (const float*)d_in[3];
    float* out = (float*)d_out;

    float* ws = (float*)d_ws;
    float*     pp1   = ws;                           // 32768
    float*     pp2   = ws + 32768;                   // 32768
    _Float16*  fragB = (_Float16*)(ws + 65536);      // 262144 halves
    _Float16*  fragA = (_Float16*)(ws + 196608);     // 262144 halves
    float*     regp  = ws + 327680;                  // 8192
    float*     part  = ws + 335872;                  // 2*3*8192 = 49152

    kA_prep<<<ROWS_TOT / 64, 64, 0, stream>>>(pts, f1, f2, pp1, pp2,
                                              fragA, fragB, regp, out);
    kB_main<<<512, 512, 0, stream>>>(pp1, pp2, fragA, fragB, part);
    k2_final<<<ROWS_TOT / 256, 256, 0, stream>>>(part, regp, wg, out);
}